// Round 3
// baseline (135319.922 us; speedup 1.0000x reference)
//
#include <hip/hip_runtime.h>
#include <cstdint>
#include <cstddef>

#define BB 128
#define TT 512
#define VV 512
#define EE 512
#define HH 1024
#define G4H 4096
#define KC 512   // K-chunk size for split-K partials

// ---------- threefry2x32, JAX *partitionable* scheme (default since jax 0.4.30) ----------
// u = jax.random.uniform(key(1), (T,B)): per-element 64-bit flat index idx,
// x0 = idx>>32 (= 0 here), x1 = idx&0xffffffff; key = (0,1);
// 32-bit bits = out0 ^ out1; float = bitcast((bits>>9)|0x3f800000) - 1.
__device__ __forceinline__ float tf_uniform(unsigned i) {
  unsigned x0 = 0u;
  unsigned x1 = i;
  const unsigned k0 = 0u, k1 = 1u, k2 = 0x1BD11BDBu; // 0x1BD11BDA ^ 0 ^ 1
  x0 += k0; x1 += k1;
#define ROTL_(v, r) (((v) << (r)) | ((v) >> (32 - (r))))
#define RND_(r) { x0 += x1; x1 = ROTL_(x1, (r)); x1 ^= x0; }
  RND_(13) RND_(15) RND_(26) RND_(6)   x0 += k1; x1 += k2 + 1u;
  RND_(17) RND_(29) RND_(16) RND_(24)  x0 += k2; x1 += k0 + 2u;
  RND_(13) RND_(15) RND_(26) RND_(6)   x0 += k0; x1 += k1 + 3u;
  RND_(17) RND_(29) RND_(16) RND_(24)  x0 += k1; x1 += k2 + 4u;
  RND_(13) RND_(15) RND_(26) RND_(6)   x0 += k2; x1 += k0 + 5u;
#undef RND_
#undef ROTL_
  unsigned bits = x0 ^ x1;
  unsigned fb = (bits >> 9) | 0x3f800000u;
  return __uint_as_float(fb) - 1.0f;
}

// ---------- init: zero h/c state, seed tok with seq[:,0] ----------
__global__ __launch_bounds__(256) void init_kernel(float* __restrict__ h0a,
                                                   float* __restrict__ c0,
                                                   float* __restrict__ h1a,
                                                   float* __restrict__ c1,
                                                   int* __restrict__ tok,
                                                   const int* __restrict__ seq) {
  int tid = blockIdx.x * 256 + threadIdx.x;
  if (tid < BB * HH) {
    h0a[tid] = 0.f; c0[tid] = 0.f; h1a[tid] = 0.f; c1[tid] = 0.f;
  }
  if (tid < BB) tok[tid] = seq[(size_t)tid * TT];  // t=0 is always teacher-forced
}

// ---------- gates GEMM: partial sums of [128,4096] over K-chunks of 512 ----------
// blockIdx.x: n-tile (32 tiles of 128 cols); blockIdx.y = s (K-chunk slot).
// s < nc1 -> operand A1/W1 (optionally emb-gather via tok[]); else A2/W2.
__global__ __launch_bounds__(256) void gates_kernel(
    const float* __restrict__ A1, int nc1, int ld1, const float* __restrict__ W1,
    const float* __restrict__ A2, int ld2, const float* __restrict__ W2,
    int gather1,
    const float* __restrict__ emb,
    const int* __restrict__ tok,
    float* __restrict__ gpart) {
  __shared__ float Xs[32][132];
  __shared__ float Ws[32][132];
  __shared__ int tok_s[BB];

  const int tid = threadIdx.x;
  const int s = blockIdx.y;
  const int n0 = blockIdx.x * 128;

  const float* A; const float* W; int ldk, koff, gath;
  if (s < nc1) { A = A1; W = W1; ldk = ld1; koff = s * KC; gath = gather1; }
  else         { A = A2; W = W2; ldk = ld2; koff = (s - nc1) * KC; gath = 0; }

  if (gath) {
    if (tid < BB) tok_s[tid] = tok[tid];
    __syncthreads();
  }

  const int ty = tid >> 4;   // 0..15 (batch groups of 8)
  const int tx = tid & 15;   // 0..15 (col groups of 8)

  float acc[8][8];
#pragma unroll
  for (int i = 0; i < 8; ++i)
#pragma unroll
    for (int jj = 0; jj < 8; ++jj) acc[i][jj] = 0.f;

  for (int kt = 0; kt < 16; ++kt) {  // 16 tiles of 32 -> KC = 512
#pragma unroll
    for (int i = 0; i < 4; ++i) {
      int f = tid + i * 256;
      int row = f >> 3;
      int kq = f & 7;
      int kg = koff + kt * 32 + kq * 4;
      float4 v;
      if (gath) {
        int tk = tok_s[row];
        if (tk == 0) v = make_float4(0.f, 0.f, 0.f, 0.f);  // padding_idx row zeroed
        else v = *(const float4*)(emb + (size_t)tk * ldk + kg);
      } else {
        v = *(const float4*)(A + (size_t)row * ldk + kg);
      }
      int kk = kq * 4;
      Xs[kk + 0][row] = v.x; Xs[kk + 1][row] = v.y;
      Xs[kk + 2][row] = v.z; Xs[kk + 3][row] = v.w;
      float4 w = *(const float4*)(W + (size_t)(n0 + row) * ldk + kg);
      Ws[kk + 0][row] = w.x; Ws[kk + 1][row] = w.y;
      Ws[kk + 2][row] = w.z; Ws[kk + 3][row] = w.w;
    }
    __syncthreads();
#pragma unroll 8
    for (int k = 0; k < 32; ++k) {
      float a[8], bb[8];
      *(float4*)&a[0] = *(const float4*)&Xs[k][ty * 8];
      *(float4*)&a[4] = *(const float4*)&Xs[k][ty * 8 + 4];
      *(float4*)&bb[0] = *(const float4*)&Ws[k][tx * 8];
      *(float4*)&bb[4] = *(const float4*)&Ws[k][tx * 8 + 4];
#pragma unroll
      for (int i = 0; i < 8; ++i)
#pragma unroll
        for (int jj = 0; jj < 8; ++jj)
          acc[i][jj] = fmaf(a[i], bb[jj], acc[i][jj]);
    }
    __syncthreads();
  }

  float* gp = gpart + (size_t)s * BB * G4H;
#pragma unroll
  for (int i = 0; i < 8; ++i) {
    int b = ty * 8 + i;
    float* dst = gp + (size_t)b * G4H + n0 + tx * 8;
    *(float4*)dst       = make_float4(acc[i][0], acc[i][1], acc[i][2], acc[i][3]);
    *(float4*)(dst + 4) = make_float4(acc[i][4], acc[i][5], acc[i][6], acc[i][7]);
  }
}

// ---------- reduce partials + bias + LSTM cell ----------
__global__ __launch_bounds__(256) void cell_kernel(
    const float* __restrict__ gpart, int S,
    const float* __restrict__ bih, const float* __restrict__ bhh,
    float* __restrict__ c, float* __restrict__ h_out) {
  int tid = blockIdx.x * 256 + threadIdx.x;  // 0..131071
  int b = tid >> 10;
  int u = tid & 1023;
  float gi = bih[u] + bhh[u];
  float gf = bih[HH + u] + bhh[HH + u];
  float gg = bih[2 * HH + u] + bhh[2 * HH + u];
  float go = bih[3 * HH + u] + bhh[3 * HH + u];
  for (int s = 0; s < S; ++s) {
    const float* gp = gpart + ((size_t)(s * BB + b)) * G4H + u;
    gi += gp[0];
    gf += gp[HH];
    gg += gp[2 * HH];
    go += gp[3 * HH];
  }
  float i_ = 1.f / (1.f + expf(-gi));
  float f_ = 1.f / (1.f + expf(-gf));
  float g_ = tanhf(gg);
  float o_ = 1.f / (1.f + expf(-go));
  float cn = f_ * c[tid] + i_ * g_;
  c[tid] = cn;
  h_out[tid] = o_ * tanhf(cn);
}

// ---------- fc: logits [128,512] K=1024, bias, write d_out ----------
__global__ __launch_bounds__(256) void fc_kernel(
    const float* __restrict__ h1,
    const float* __restrict__ fcw, const float* __restrict__ fcb,
    float* __restrict__ out, int t) {
  __shared__ float Xs[32][132];
  __shared__ float Wsh[32][20];
  const int tid = threadIdx.x;
  const int n0 = blockIdx.x * 16;  // 32 blocks
  const int tb = tid >> 3;  // 0..31 (4 batch rows each)
  const int tn = tid & 7;   // 0..7  (2 cols each)
  float acc[4][2] = {{0.f, 0.f}, {0.f, 0.f}, {0.f, 0.f}, {0.f, 0.f}};

  for (int kt = 0; kt < 32; ++kt) {
#pragma unroll
    for (int i = 0; i < 4; ++i) {
      int f = tid + i * 256;
      int row = f >> 3, kq = f & 7;
      float4 v = *(const float4*)(h1 + (size_t)row * HH + kt * 32 + kq * 4);
      int kk = kq * 4;
      Xs[kk + 0][row] = v.x; Xs[kk + 1][row] = v.y;
      Xs[kk + 2][row] = v.z; Xs[kk + 3][row] = v.w;
    }
    if (tid < 128) {
      int row = tid >> 3, kq = tid & 7;
      float4 v = *(const float4*)(fcw + (size_t)(n0 + row) * HH + kt * 32 + kq * 4);
      int kk = kq * 4;
      Wsh[kk + 0][row] = v.x; Wsh[kk + 1][row] = v.y;
      Wsh[kk + 2][row] = v.z; Wsh[kk + 3][row] = v.w;
    }
    __syncthreads();
#pragma unroll 8
    for (int k = 0; k < 32; ++k) {
      float4 a = *(const float4*)&Xs[k][tb * 4];
      float b0 = Wsh[k][tn * 2], b1 = Wsh[k][tn * 2 + 1];
      acc[0][0] = fmaf(a.x, b0, acc[0][0]); acc[0][1] = fmaf(a.x, b1, acc[0][1]);
      acc[1][0] = fmaf(a.y, b0, acc[1][0]); acc[1][1] = fmaf(a.y, b1, acc[1][1]);
      acc[2][0] = fmaf(a.z, b0, acc[2][0]); acc[2][1] = fmaf(a.z, b1, acc[2][1]);
      acc[3][0] = fmaf(a.w, b0, acc[3][0]); acc[3][1] = fmaf(a.w, b1, acc[3][1]);
    }
    __syncthreads();
  }

#pragma unroll
  for (int i = 0; i < 4; ++i) {
    int b = tb * 4 + i;
#pragma unroll
    for (int jj = 0; jj < 2; ++jj) {
      int n = n0 + tn * 2 + jj;
      out[((size_t)b * TT + t) * VV + n] = acc[i][jj] + fcb[n];
    }
  }
}

// ---------- token select for step t+1: teacher-forcing draw + serial first-argmax ----------
// Reads this step's logits straight from d_out -> feedback is bit-identical to emitted output.
__global__ __launch_bounds__(128) void argsel_kernel(
    const float* __restrict__ out, const int* __restrict__ seq,
    const float* __restrict__ teacher_p, int t, int* __restrict__ tok) {
  int b = threadIdx.x;  // 128 threads, one per batch row
  float uu = tf_uniform((unsigned)((t + 1) * BB + b));
  int sel;
  if (uu < teacher_p[0]) {
    sel = seq[(size_t)b * TT + (t + 1)];
  } else {
    const float* row = out + ((size_t)b * TT + t) * VV;
    float best = row[0];
    int bi = 0;
    for (int v = 1; v < VV; ++v) {
      float x = row[v];
      if (x > best) { best = x; bi = v; }  // strict > == np.argmax first-max
    }
    sel = bi;
  }
  tok[b] = sel;
}

extern "C" void kernel_launch(void* const* d_in, const int* in_sizes, int n_in,
                              void* d_out, int out_size, void* d_ws, size_t ws_size,
                              hipStream_t stream) {
  const int*   seq       = (const int*)d_in[0];
  const float* teacher_p = (const float*)d_in[2];
  const float* embeds    = (const float*)d_in[3];
  const float* W_ih0     = (const float*)d_in[4];
  const float* W_hh0     = (const float*)d_in[5];
  const float* b_ih0     = (const float*)d_in[6];
  const float* b_hh0     = (const float*)d_in[7];
  const float* W_ih1     = (const float*)d_in[8];
  const float* W_hh1     = (const float*)d_in[9];
  const float* b_ih1     = (const float*)d_in[10];
  const float* b_hh1     = (const float*)d_in[11];
  const float* fc_w      = (const float*)d_in[12];
  const float* fc_b      = (const float*)d_in[13];
  float* out = (float*)d_out;

  // workspace layout (bytes): states 3.0 MB + tok + gpart 8 MB  (~11.5 MB total)
  char* ws = (char*)d_ws;
  const size_t BH = (size_t)BB * HH;            // 131072 floats
  float* h0    = (float*)(ws);                  // 2 * BH (ping-pong)
  float* c0    = (float*)(ws + 2 * BH * 4);     // BH
  float* h1    = (float*)(ws + 3 * BH * 4);     // 2 * BH (ping-pong)
  float* c1    = (float*)(ws + 5 * BH * 4);     // BH
  int*   tok   = (int*)(ws + 6 * BH * 4);       // 128 ints (padded to 4096 B)
  float* gpart = (float*)(ws + 6 * BH * 4 + 4096);  // 4 * 128 * 4096 floats = 8 MB

  init_kernel<<<512, 256, 0, stream>>>(h0, c0, h1, c1, tok, seq);

  for (int t = 0; t < TT; ++t) {
    float* h0r = h0 + (size_t)(t & 1) * BH;
    float* h0w = h0 + (size_t)((t + 1) & 1) * BH;
    float* h1r = h1 + (size_t)(t & 1) * BH;
    float* h1w = h1 + (size_t)((t + 1) & 1) * BH;

    // layer 0: x = emb[tok] (K=512, 1 chunk) + h0r (K=1024, 2 chunks)
    gates_kernel<<<dim3(32, 3), 256, 0, stream>>>(
        nullptr, 1, EE, W_ih0, h0r, HH, W_hh0, /*gather1=*/1,
        embeds, tok, gpart);
    cell_kernel<<<512, 256, 0, stream>>>(gpart, 3, b_ih0, b_hh0, c0, h0w);

    // layer 1: h0w (K=1024, 2 chunks) + h1r (K=1024, 2 chunks)
    gates_kernel<<<dim3(32, 4), 256, 0, stream>>>(
        h0w, 2, HH, W_ih1, h1r, HH, W_hh1, /*gather1=*/0,
        embeds, tok, gpart);
    cell_kernel<<<512, 256, 0, stream>>>(gpart, 4, b_ih1, b_hh1, c1, h1w);

    // fc: logits -> d_out
    fc_kernel<<<32, 256, 0, stream>>>(h1w, fc_w, fc_b, out, t);

    // token for step t+1 (teacher draw or argmax of this step's logits)
    if (t < TT - 1) {
      argsel_kernel<<<1, 128, 0, stream>>>(out, seq, teacher_p, t, tok);
    }
  }
}

// Round 4
// 90182.452 us; speedup vs baseline: 1.5005x; 1.5005x over previous
//
#include <hip/hip_runtime.h>
#include <cstdint>
#include <cstddef>

#define BB 128
#define TT 512
#define VV 512
#define EE 512
#define HH 1024
#define G4H 4096
#define KC 256   // K-chunk size for split-K partials

// ---------- threefry2x32, JAX *partitionable* scheme (default since jax 0.4.30) ----------
// VERIFIED round 3: passed with absmax 4.9e-4. Do not touch.
__device__ __forceinline__ float tf_uniform(unsigned i) {
  unsigned x0 = 0u;
  unsigned x1 = i;
  const unsigned k0 = 0u, k1 = 1u, k2 = 0x1BD11BDBu; // 0x1BD11BDA ^ 0 ^ 1
  x0 += k0; x1 += k1;
#define ROTL_(v, r) (((v) << (r)) | ((v) >> (32 - (r))))
#define RND_(r) { x0 += x1; x1 = ROTL_(x1, (r)); x1 ^= x0; }
  RND_(13) RND_(15) RND_(26) RND_(6)   x0 += k1; x1 += k2 + 1u;
  RND_(17) RND_(29) RND_(16) RND_(24)  x0 += k2; x1 += k0 + 2u;
  RND_(13) RND_(15) RND_(26) RND_(6)   x0 += k0; x1 += k1 + 3u;
  RND_(17) RND_(29) RND_(16) RND_(24)  x0 += k1; x1 += k2 + 4u;
  RND_(13) RND_(15) RND_(26) RND_(6)   x0 += k2; x1 += k0 + 5u;
#undef RND_
#undef ROTL_
  unsigned bits = x0 ^ x1;
  unsigned fb = (bits >> 9) | 0x3f800000u;
  return __uint_as_float(fb) - 1.0f;
}

// ---------- init: zero h/c state ----------
__global__ __launch_bounds__(256) void init_kernel(float* __restrict__ h0a,
                                                   float* __restrict__ c0,
                                                   float* __restrict__ h1a,
                                                   float* __restrict__ c1) {
  int tid = blockIdx.x * 256 + threadIdx.x;
  if (tid < BB * HH) {
    h0a[tid] = 0.f; c0[tid] = 0.f; h1a[tid] = 0.f; c1[tid] = 0.f;
  }
}

// ---------- gates GEMM: partial sums of [128,4096] over K-chunks of 256 ----------
// blockIdx.x: n-tile (32 tiles of 128 cols); blockIdx.y = s (K-chunk slot).
// s < nc1 -> operand A1/W1 (emb-gather when gather1); else A2/W2.
// Gather blocks ALSO select this step's token inline (teacher draw vs argmax of
// prev step's fc partials) — deterministic, redundantly computed per gather block.
__global__ __launch_bounds__(256) void gates_kernel(
    const float* __restrict__ A1, int nc1, int ld1, const float* __restrict__ W1,
    const float* __restrict__ A2, int ld2, const float* __restrict__ W2,
    int gather1,
    const float* __restrict__ emb,
    const int* __restrict__ seq,
    const float* __restrict__ teacher_p,
    const unsigned long long* __restrict__ fcpart,
    int t,
    float* __restrict__ gpart) {
  __shared__ float Xs[32][132];
  __shared__ float Ws[32][132];
  __shared__ int tok_s[BB];

  const int tid = threadIdx.x;
  const int s = blockIdx.y;
  const int n0 = blockIdx.x * 128;

  const float* A; const float* W; int ldk, koff, gath;
  if (s < nc1) { A = A1; W = W1; ldk = ld1; koff = s * KC; gath = gather1; }
  else         { A = A2; W = W2; ldk = ld2; koff = (s - nc1) * KC; gath = 0; }

  if (gath) {
    if (tid < BB) {
      int sel;
      if (t == 0) {
        sel = seq[(size_t)tid * TT];  // t=0 always teacher-forced
      } else {
        float uu = tf_uniform((unsigned)(t * BB + tid));
        if (uu < teacher_p[0]) {
          sel = seq[(size_t)tid * TT + t];
        } else {
          const unsigned long long* fp = fcpart + (size_t)tid * 32;
          unsigned long long best = fp[0];
#pragma unroll 8
          for (int j = 1; j < 32; ++j) {
            unsigned long long k2 = fp[j];
            if (k2 > best) best = k2;
          }
          sel = (int)(0xFFFFFFFFu - (unsigned)(best & 0xFFFFFFFFull));
        }
      }
      tok_s[tid] = sel;
    }
    __syncthreads();
  }

  const int ty = tid >> 4;   // 0..15; within a wave only 0..3 -> A-reads broadcast
  const int tx = tid & 15;   // 0..15

  // fragment mapping: rows {ty*4+i, 64+ty*4+i}, cols {tx*4+j, 64+tx*4+j}
  // -> wave LDS reads: A broadcast (free), B 2-way bank alias (free, m136)
  float acc[8][8];
#pragma unroll
  for (int i = 0; i < 8; ++i)
#pragma unroll
    for (int jj = 0; jj < 8; ++jj) acc[i][jj] = 0.f;

  for (int kt = 0; kt < 8; ++kt) {  // 8 tiles of 32 -> KC = 256
#pragma unroll
    for (int i = 0; i < 4; ++i) {
      int f = tid + i * 256;
      int row = f >> 3;
      int kq = f & 7;
      int kg = koff + kt * 32 + kq * 4;
      float4 v;
      if (gath) {
        int tk = tok_s[row];
        if (tk == 0) v = make_float4(0.f, 0.f, 0.f, 0.f);  // padding_idx row zeroed
        else v = *(const float4*)(emb + (size_t)tk * ldk + kg);
      } else {
        v = *(const float4*)(A + (size_t)row * ldk + kg);
      }
      int kk = kq * 4;
      Xs[kk + 0][row] = v.x; Xs[kk + 1][row] = v.y;
      Xs[kk + 2][row] = v.z; Xs[kk + 3][row] = v.w;
      float4 w = *(const float4*)(W + (size_t)(n0 + row) * ldk + kg);
      Ws[kk + 0][row] = w.x; Ws[kk + 1][row] = w.y;
      Ws[kk + 2][row] = w.z; Ws[kk + 3][row] = w.w;
    }
    __syncthreads();
#pragma unroll 8
    for (int k = 0; k < 32; ++k) {
      float a[8], bb[8];
      *(float4*)&a[0] = *(const float4*)&Xs[k][ty * 4];
      *(float4*)&a[4] = *(const float4*)&Xs[k][64 + ty * 4];
      *(float4*)&bb[0] = *(const float4*)&Ws[k][tx * 4];
      *(float4*)&bb[4] = *(const float4*)&Ws[k][64 + tx * 4];
#pragma unroll
      for (int i = 0; i < 8; ++i)
#pragma unroll
        for (int jj = 0; jj < 8; ++jj)
          acc[i][jj] = fmaf(a[i], bb[jj], acc[i][jj]);
    }
    __syncthreads();
  }

  float* gp = gpart + (size_t)s * BB * G4H;
#pragma unroll
  for (int ih = 0; ih < 2; ++ih) {
#pragma unroll
    for (int i = 0; i < 4; ++i) {
      int b = ih * 64 + ty * 4 + i;
      int ai = ih * 4 + i;
      float* dst = gp + (size_t)b * G4H + n0;
      *(float4*)(dst + tx * 4) =
          make_float4(acc[ai][0], acc[ai][1], acc[ai][2], acc[ai][3]);
      *(float4*)(dst + 64 + tx * 4) =
          make_float4(acc[ai][4], acc[ai][5], acc[ai][6], acc[ai][7]);
    }
  }
}

// ---------- reduce partials + bias + LSTM cell ----------
__global__ __launch_bounds__(256) void cell_kernel(
    const float* __restrict__ gpart, int S,
    const float* __restrict__ bih, const float* __restrict__ bhh,
    float* __restrict__ c, float* __restrict__ h_out) {
  int tid = blockIdx.x * 256 + threadIdx.x;  // 0..131071
  int b = tid >> 10;
  int u = tid & 1023;
  float gi = bih[u] + bhh[u];
  float gf = bih[HH + u] + bhh[HH + u];
  float gg = bih[2 * HH + u] + bhh[2 * HH + u];
  float go = bih[3 * HH + u] + bhh[3 * HH + u];
  for (int s = 0; s < S; ++s) {
    const float* gp = gpart + ((size_t)(s * BB + b)) * G4H + u;
    gi += gp[0];
    gf += gp[HH];
    gg += gp[2 * HH];
    go += gp[3 * HH];
  }
  float i_ = 1.f / (1.f + expf(-gi));
  float f_ = 1.f / (1.f + expf(-gf));
  float g_ = tanhf(gg);
  float o_ = 1.f / (1.f + expf(-go));
  float cn = f_ * c[tid] + i_ * g_;
  c[tid] = cn;
  h_out[tid] = o_ * tanhf(cn);
}

// ---------- fc: logits [128,512] K=1024 + bias -> d_out, plus per-(row,tile) argmax key ----------
// Key packs (total-order float bits, 0xFFFFFFFF - n): max key == first-max argmax.
// Single writer per fcpart slot -> deterministic (no atomics).
__global__ __launch_bounds__(256) void fc_kernel(
    const float* __restrict__ h1,
    const float* __restrict__ fcw, const float* __restrict__ fcb,
    float* __restrict__ out, unsigned long long* __restrict__ fcpart, int t) {
  __shared__ float Xs[32][132];
  __shared__ float Wsh[32][20];
  const int tid = threadIdx.x;
  const int n0 = blockIdx.x * 16;  // 32 blocks
  const int tb = tid >> 3;  // 0..31 (4 batch rows each)
  const int tn = tid & 7;   // 0..7  (2 cols each)
  float acc[4][2] = {{0.f, 0.f}, {0.f, 0.f}, {0.f, 0.f}, {0.f, 0.f}};

  for (int kt = 0; kt < 32; ++kt) {
#pragma unroll
    for (int i = 0; i < 4; ++i) {
      int f = tid + i * 256;
      int row = f >> 3, kq = f & 7;
      float4 v = *(const float4*)(h1 + (size_t)row * HH + kt * 32 + kq * 4);
      int kk = kq * 4;
      Xs[kk + 0][row] = v.x; Xs[kk + 1][row] = v.y;
      Xs[kk + 2][row] = v.z; Xs[kk + 3][row] = v.w;
    }
    if (tid < 128) {
      int row = tid >> 3, kq = tid & 7;
      float4 v = *(const float4*)(fcw + (size_t)(n0 + row) * HH + kt * 32 + kq * 4);
      int kk = kq * 4;
      Wsh[kk + 0][row] = v.x; Wsh[kk + 1][row] = v.y;
      Wsh[kk + 2][row] = v.z; Wsh[kk + 3][row] = v.w;
    }
    __syncthreads();
#pragma unroll 8
    for (int k = 0; k < 32; ++k) {
      float4 a = *(const float4*)&Xs[k][tb * 4];
      float b0 = Wsh[k][tn * 2], b1 = Wsh[k][tn * 2 + 1];
      acc[0][0] = fmaf(a.x, b0, acc[0][0]); acc[0][1] = fmaf(a.x, b1, acc[0][1]);
      acc[1][0] = fmaf(a.y, b0, acc[1][0]); acc[1][1] = fmaf(a.y, b1, acc[1][1]);
      acc[2][0] = fmaf(a.z, b0, acc[2][0]); acc[2][1] = fmaf(a.z, b1, acc[2][1]);
      acc[3][0] = fmaf(a.w, b0, acc[3][0]); acc[3][1] = fmaf(a.w, b1, acc[3][1]);
    }
    __syncthreads();
  }

#pragma unroll
  for (int i = 0; i < 4; ++i) {
    int b = tb * 4 + i;
    unsigned long long key = 0ull;
#pragma unroll
    for (int jj = 0; jj < 2; ++jj) {
      int n = n0 + tn * 2 + jj;
      float lg = acc[i][jj] + fcb[n];
      out[((size_t)b * TT + t) * VV + n] = lg;
      unsigned sbits = __float_as_uint(lg);
      sbits = (sbits & 0x80000000u) ? ~sbits : (sbits | 0x80000000u);
      unsigned long long kk =
          ((unsigned long long)sbits << 32) |
          (unsigned long long)(0xFFFFFFFFu - (unsigned)n);
      if (kk > key) key = kk;
    }
#pragma unroll
    for (int off = 4; off > 0; off >>= 1) {
      unsigned long long o = __shfl_down(key, off, 8);
      if (o > key) key = o;
    }
    if (tn == 0) fcpart[(size_t)b * 32 + blockIdx.x] = key;
  }
}

extern "C" void kernel_launch(void* const* d_in, const int* in_sizes, int n_in,
                              void* d_out, int out_size, void* d_ws, size_t ws_size,
                              hipStream_t stream) {
  const int*   seq       = (const int*)d_in[0];
  const float* teacher_p = (const float*)d_in[2];
  const float* embeds    = (const float*)d_in[3];
  const float* W_ih0     = (const float*)d_in[4];
  const float* W_hh0     = (const float*)d_in[5];
  const float* b_ih0     = (const float*)d_in[6];
  const float* b_hh0     = (const float*)d_in[7];
  const float* W_ih1     = (const float*)d_in[8];
  const float* W_hh1     = (const float*)d_in[9];
  const float* b_ih1     = (const float*)d_in[10];
  const float* b_hh1     = (const float*)d_in[11];
  const float* fc_w      = (const float*)d_in[12];
  const float* fc_b      = (const float*)d_in[13];
  float* out = (float*)d_out;

  // workspace layout (bytes): states 3 MB + fcpart 32 KB + gpart 16 MB  (~19.1 MB)
  char* ws = (char*)d_ws;
  const size_t BH = (size_t)BB * HH;            // 131072 floats
  float* h0    = (float*)(ws);                  // 2 * BH (ping-pong)
  float* c0    = (float*)(ws + 2 * BH * 4);     // BH
  float* h1    = (float*)(ws + 3 * BH * 4);     // 2 * BH (ping-pong)
  float* c1    = (float*)(ws + 5 * BH * 4);     // BH
  unsigned long long* fcpart = (unsigned long long*)(ws + 6 * BH * 4);  // 128*32 u64
  float* gpart = (float*)(ws + 6 * BH * 4 + 65536);  // 8 * 128 * 4096 floats = 16 MB

  init_kernel<<<512, 256, 0, stream>>>(h0, c0, h1, c1);

  for (int t = 0; t < TT; ++t) {
    float* h0r = h0 + (size_t)(t & 1) * BH;
    float* h0w = h0 + (size_t)((t + 1) & 1) * BH;
    float* h1r = h1 + (size_t)(t & 1) * BH;
    float* h1w = h1 + (size_t)((t + 1) & 1) * BH;

    // layer 0: x = emb[tok] (K=512, 2 chunks) + h0r (K=1024, 4 chunks) -> 192 blocks
    gates_kernel<<<dim3(32, 6), 256, 0, stream>>>(
        nullptr, 2, EE, W_ih0, h0r, HH, W_hh0, /*gather1=*/1,
        embeds, seq, teacher_p, fcpart, t, gpart);
    cell_kernel<<<512, 256, 0, stream>>>(gpart, 6, b_ih0, b_hh0, c0, h0w);

    // layer 1: h0w (K=1024, 4 chunks) + h1r (K=1024, 4 chunks) -> 256 blocks
    gates_kernel<<<dim3(32, 8), 256, 0, stream>>>(
        h0w, 4, HH, W_ih1, h1r, HH, W_hh1, /*gather1=*/0,
        embeds, seq, teacher_p, fcpart, t, gpart);
    cell_kernel<<<512, 256, 0, stream>>>(gpart, 8, b_ih1, b_hh1, c1, h1w);

    // fc: logits -> d_out, argmax partials -> fcpart (consumed by next step's gates0)
    fc_kernel<<<32, 256, 0, stream>>>(h1w, fc_w, fc_b, out, fcpart, t);
  }
}